// Round 1
// baseline (183.940 us; speedup 1.0000x reference)
//
#include <hip/hip_runtime.h>

// Ray termination probability scan along depth.
// voxels: [B=16, D=128, H=128, W=128] fp32, row-major (W contiguous).
// out[b, H-1-h, w] = sum_{d} o[b,d,h,w] * T_d,
//   o = clip(v, EPS, 1-EPS), T_0 = exp(EPS), T_d = prod_{k<d}(1-o_k).
// Direct-product form of the reference's exp(cumsum(log(1-o))) -- identical math.

#define EPS 1e-5f
#define EXP_EPS 1.0000100000500002f  // expf(1e-5f)

#define B_ 16
#define D_ 128
#define H_ 128
#define W_ 128

__device__ __forceinline__ float clampo(float v) {
    return fminf(fmaxf(v, EPS), 1.0f - EPS);
}

__global__ __launch_bounds__(128) void ray_term_kernel(const float* __restrict__ vox,
                                                       float* __restrict__ out) {
    const int w4 = threadIdx.x;                          // 0..31 -> w = 4*w4..4*w4+3
    const int h  = blockIdx.x * blockDim.y + threadIdx.y; // blockDim.y = 4
    const int b  = blockIdx.y;

    // base points at [b, d=0, h, 4*w4]
    const float4* __restrict__ src =
        (const float4*)(vox + ((size_t)b * D_ * H_ + (size_t)h) * W_) + w4;
    const int dstride = H_ * W_ / 4;  // float4 stride between depth slices

    // d = 0 peeled: carries the exp(EPS) factor from the eps slab.
    float4 v0 = src[0];
    float o0 = clampo(v0.x), o1 = clampo(v0.y), o2 = clampo(v0.z), o3 = clampo(v0.w);
    float a0 = o0 * EXP_EPS, a1 = o1 * EXP_EPS, a2 = o2 * EXP_EPS, a3 = o3 * EXP_EPS;
    float T0 = 1.0f - o0, T1 = 1.0f - o1, T2 = 1.0f - o2, T3 = 1.0f - o3;

    #pragma unroll 8
    for (int d = 1; d < D_; ++d) {
        float4 v = src[(size_t)d * dstride];
        o0 = clampo(v.x); o1 = clampo(v.y); o2 = clampo(v.z); o3 = clampo(v.w);
        a0 = fmaf(o0, T0, a0); T0 *= (1.0f - o0);
        a1 = fmaf(o1, T1, a1); T1 *= (1.0f - o1);
        a2 = fmaf(o2, T2, a2); T2 *= (1.0f - o2);
        a3 = fmaf(o3, T3, a3); T3 *= (1.0f - o3);
    }

    // vertical flip along H on output
    float* __restrict__ dst =
        out + ((size_t)b * H_ + (size_t)(H_ - 1 - h)) * W_ + 4 * w4;
    *(float4*)dst = make_float4(a0, a1, a2, a3);
}

extern "C" void kernel_launch(void* const* d_in, const int* in_sizes, int n_in,
                              void* d_out, int out_size, void* d_ws, size_t ws_size,
                              hipStream_t stream) {
    const float* vox = (const float*)d_in[0];
    float* out = (float*)d_out;
    dim3 block(32, 4, 1);           // 128 threads = 2 waves
    dim3 grid(H_ / 4, B_, 1);       // 32 x 16 = 512 blocks
    ray_term_kernel<<<grid, block, 0, stream>>>(vox, out);
}